// Round 19
// baseline (118.064 us; speedup 1.0000x reference)
//
#include <hip/hip_runtime.h>
#include <math.h>

#define NPTS 32768
#define NB 2
#define CIN 32
#define H 32
#define D 64
#define DOUT 128
#define BN_RS 0.99999500003749981f   // 1/sqrt(1 + 1e-5)
#define LOG2E 1.44269504088896341f

typedef __attribute__((ext_vector_type(8))) short bf16x8;
typedef __attribute__((ext_vector_type(4))) short bf16x4;
typedef __attribute__((ext_vector_type(4))) float f32x4;

__device__ __forceinline__ ushort f2b(float f) {
    union { float f; unsigned u; } v; v.f = f;
    unsigned r = v.u + 0x7fffu + ((v.u >> 16) & 1u);   // RNE
    return (ushort)(r >> 16);
}
__device__ __forceinline__ float b2f(ushort u) {
    union { unsigned u; float f; } v; v.u = ((unsigned)u) << 16; return v.f;
}
// pack two f32 -> bf16x2 dword via gfx950 v_cvt_pk_bf16_f32 (1 inst); lo = f0, hi = f1
__device__ __forceinline__ unsigned pk2(float f0, float f1) {
    unsigned r;
    asm("v_cvt_pk_bf16_f32 %0, %1, %2" : "=v"(r) : "v"(f0), "v"(f1));
    return r;
}
// unpack (Q,E) dword -> Q/E
__device__ __forceinline__ float qdiv(unsigned u) {
    float q = __builtin_bit_cast(float, u << 16);
    float e = __builtin_bit_cast(float, u & 0xffff0000u);
    return __fdividef(q, e);
}
// raw 2^x (weights pre-scaled by log2e)
__device__ __forceinline__ float ex2(float x) {
    float r; asm("v_exp_f32 %0, %1" : "=v"(r) : "v"(x)); return r;
}
// cross-row sums via gfx950 permlane swaps (VALU pipe, no DS)
__device__ __forceinline__ float xsum16(float x) {
    float a = x, b = x;
    asm("v_permlane16_swap_b32 %0, %1" : "+v"(a), "+v"(b));
    return a + b;
}
__device__ __forceinline__ float xsum32(float x) {
    float a = x, b = x;
    asm("v_permlane32_swap_b32 %0, %1" : "+v"(a), "+v"(b));
    return a + b;
}
#define MF(a, b, c) __builtin_amdgcn_mfma_f32_16x16x32_bf16(a, b, c, 0, 0, 0)

// WBX: write relu'd C tile (mi,ni) to feat cols 32..63  (C: row=channel, col=position)
#define WBX(mi, ni, A) { uint2 _w;                                                \
    _w.x = pk2(fmaxf(A[0], 0.f), fmaxf(A[1], 0.f));                               \
    _w.y = pk2(fmaxf(A[2], 0.f), fmaxf(A[3], 0.f));                               \
    *(uint2*)&feat[wid][(ni) * 16 + c16][32 + (mi) * 16 + g4] = _w; }

// ---- transposed attention core: L^T = feat @ fc^T -> k on rows ----
#define ATT_CG(ni, cg, F0, F1, AF, SEL) {                                         \
    f32x4 ac = zf4;                                                               \
    ac = MF(a0_, F0, ac);                                                         \
    ac = MF(a1_, F1, ac);                                                         \
    f32x4 fv4 = MF(AF, SEL, zf4);                                                 \
    float e0 = ex2(ac[0]), e1 = ex2(ac[1]), e2 = ex2(ac[2]), e3 = ex2(ac[3]);     \
    float E = (e0 + e1) + (e2 + e3);                                              \
    float Q = e0 * fv4[0]; Q = fmaf(e1, fv4[1], Q);                               \
    Q = fmaf(e2, fv4[2], Q); Q = fmaf(e3, fv4[3], Q);                             \
    E = xsum32(xsum16(E));                                                        \
    Q = xsum32(xsum16(Q));                                                        \
    if (g == 0) qe[(wid << 2) + (ni)][(cg) * 16 + c16] = pk2(Q, E); }
#define ATT_NI(ni) {                                                              \
    bf16x8 a0_ = *(const bf16x8*)&feat[wid][(ni) * 16 + c16][g8];                 \
    bf16x8 a1_ = *(const bf16x8*)&feat[wid][(ni) * 16 + c16][32 + g8];            \
    ATT_CG(ni, 0, afc0_0, afc0_1, a0_, selLo.v) ATT_CG(ni, 1, afc1_0, afc1_1, a0_, selHi.v) \
    ATT_CG(ni, 2, afc2_0, afc2_1, a1_, selLo.v) ATT_CG(ni, 3, afc3_0, afc3_1, a1_, selHi.v) }

// build constant selector B-fragments: selLo[k][col]=d(k==col), selHi[k][col]=d(k==col+16)
#define MKSEL                                                                      \
    union { bf16x8 v; ushort s[8]; } selLo, selHi;                                 \
    _Pragma("unroll")                                                              \
    for (int j = 0; j < 8; ++j) {                                                  \
        selLo.s[j] = ((g8 + j) == c16)      ? (ushort)0x3F80 : (ushort)0;          \
        selHi.s[j] = ((g8 + j) == c16 + 16) ? (ushort)0x3F80 : (ushort)0;          \
    }

// build agg B-frags from qe (divide deferred to here)
#define QFRAG(bbv, base) {                                                        \
    uint4 _qa = *(const uint4*)&qe[c16][(base) + g8];                             \
    uint4 _qb = *(const uint4*)&qe[c16][(base) + g8 + 4];                         \
    bbv.u.x = pk2(qdiv(_qa.x), qdiv(_qa.y));                                      \
    bbv.u.y = pk2(qdiv(_qa.z), qdiv(_qa.w));                                      \
    bbv.u.z = pk2(qdiv(_qb.x), qdiv(_qb.y));                                      \
    bbv.u.w = pk2(qdiv(_qb.z), qdiv(_qb.w)); }

// fc B-fragments directly from prefolded global (L2-resident)
#define LOAD_AFC(SRC)                                                              \
    bf16x8 afc0_0 = *(const bf16x8*)&(SRC)[( 0 + c16) * 64 +      g8];             \
    bf16x8 afc0_1 = *(const bf16x8*)&(SRC)[( 0 + c16) * 64 + 32 + g8];             \
    bf16x8 afc1_0 = *(const bf16x8*)&(SRC)[(16 + c16) * 64 +      g8];             \
    bf16x8 afc1_1 = *(const bf16x8*)&(SRC)[(16 + c16) * 64 + 32 + g8];             \
    bf16x8 afc2_0 = *(const bf16x8*)&(SRC)[(32 + c16) * 64 +      g8];             \
    bf16x8 afc2_1 = *(const bf16x8*)&(SRC)[(32 + c16) * 64 + 32 + g8];             \
    bf16x8 afc3_0 = *(const bf16x8*)&(SRC)[(48 + c16) * 64 +      g8];             \
    bf16x8 afc3_1 = *(const bf16x8*)&(SRC)[(48 + c16) * 64 + 32 + g8];

// ---------------- Kernel 0: one-time weight prefold -> bf16 workspace ----------------
__global__ __launch_bounds__(256) void k0_prep(
    const float* __restrict__ att1_fc, const float* __restrict__ att2_fc,
    const float* __restrict__ att1_w, const float* __restrict__ att1_g,
    const float* __restrict__ att2_w, const float* __restrict__ att2_g,
    const float* __restrict__ bb_w1, const float* __restrict__ bb_g1,
    const float* __restrict__ bb_w2, const float* __restrict__ bb_g2,
    const float* __restrict__ w_mlp2, const float* __restrict__ g_mlp2,
    const float* __restrict__ w_sc, const float* __restrict__ g_sc,
    ushort* __restrict__ fcb1g, ushort* __restrict__ fcb2g,
    ushort* __restrict__ awb1g, ushort* __restrict__ awb2g,
    ushort* __restrict__ w2bg, ushort* __restrict__ w1pg,
    ushort* __restrict__ wcatg)
{
    int t = blockIdx.x * 256 + threadIdx.x;
    if (t < 4096) {
        fcb1g[t] = f2b(att1_fc[t] * LOG2E);
        fcb2g[t] = f2b(att2_fc[t] * LOG2E);
        awb2g[t] = f2b(att2_w[t] * (att2_g[t >> 6] * BN_RS));
    }
    if (t < 2048) awb1g[t] = f2b(att1_w[t] * (att1_g[t >> 6] * BN_RS));
    if (t < 1024) w2bg[t]  = f2b(bb_w2[t] * (bb_g2[t >> 5] * BN_RS));
    if (t < 1280) {
        int o = t / 40, k = t % 40;
        w1pg[t] = (k < 10) ? f2b(bb_w1[o * 10 + k] * (bb_g1[o] * BN_RS)) : (ushort)0;
    }
    if (t < 12288) {
        int o = t / 96, c = t - o * 96;
        wcatg[t] = (c < D) ? f2b(w_mlp2[o * D + c] * (g_mlp2[o] * BN_RS))
                           : f2b(w_sc[o * CIN + (c - D)] * (g_sc[o] * BN_RS));
    }
}

// ---------------- Kernel 1: f_pc = relu(bn(w_mlp1 @ feature)) -> bf16 (B*N,32) ----------------
__global__ __launch_bounds__(256, 4) void k1_mlp1(
    const float* __restrict__ feature, const float* __restrict__ w_mlp1,
    const float* __restrict__ g_mlp1, const float* __restrict__ b_mlp1,
    ushort* __restrict__ f_pc, ushort* __restrict__ featpm)
{
    int tid = threadIdx.x;
    int pg = blockIdx.x * 256 + tid;
    int b = pg >> 15, n = pg & (NPTS - 1);

    float x[CIN];
#pragma unroll
    for (int c = 0; c < CIN; ++c)
        x[c] = feature[((b * CIN + c) << 15) + n];

    float outv[CIN];
#pragma unroll
    for (int o = 0; o < CIN; ++o) {
        float s0 = 0.f, s1 = 0.f, s2 = 0.f, s3 = 0.f;
        const float* w = w_mlp1 + o * CIN;
#pragma unroll
        for (int c = 0; c < CIN; c += 4) {
            s0 = fmaf(w[c + 0], x[c + 0], s0);
            s1 = fmaf(w[c + 1], x[c + 1], s1);
            s2 = fmaf(w[c + 2], x[c + 2], s2);
            s3 = fmaf(w[c + 3], x[c + 3], s3);
        }
        float acc = (s0 + s1) + (s2 + s3);
        outv[o] = fmaxf(fmaf(acc, g_mlp1[o] * BN_RS, b_mlp1[o]), 0.f);
    }
    uint4* dst = (uint4*)(f_pc + ((size_t)pg << 5));
    uint4* dst2 = (uint4*)(featpm + ((size_t)pg << 5));
#pragma unroll
    for (int j = 0; j < 4; ++j) {
        uint4 u;
        u.x = pk2(outv[8 * j + 0], outv[8 * j + 1]);
        u.y = pk2(outv[8 * j + 2], outv[8 * j + 3]);
        u.z = pk2(outv[8 * j + 4], outv[8 * j + 5]);
        u.w = pk2(outv[8 * j + 6], outv[8 * j + 7]);
        dst[j] = u;
        uint4 v;
        v.x = pk2(x[8 * j + 0], x[8 * j + 1]);
        v.y = pk2(x[8 * j + 2], x[8 * j + 3]);
        v.z = pk2(x[8 * j + 4], x[8 * j + 5]);
        v.w = pk2(x[8 * j + 6], x[8 * j + 7]);
        dst2[j] = v;
    }
}

// ---------------- Kernel 2: stage-1 -> f_agg bf16 (B*N, 32) ----------------
__global__ __launch_bounds__(256, 3) void k2_stage1(
    const float* __restrict__ xyz, const int* __restrict__ nidx,
    const ushort* __restrict__ f_pc,
    const float* __restrict__ bb_b1,
    const ushort* __restrict__ fcb1g, const ushort* __restrict__ w1pg,
    const ushort* __restrict__ awb1g, const float* __restrict__ att_b,
    ushort* __restrict__ f_agg)
{
    __shared__ __align__(16) ushort feat[4][64][72];   // per-wave 64 pos x 64 ch bf16
    __shared__ __align__(16) unsigned qe[16][68];      // packed (Q,E) per point x channel

    int tid = threadIdx.x;
    int wid = tid >> 6, lane = tid & 63;
    int g = lane >> 4, c16 = lane & 15;
    int g4 = g << 2, g8 = g << 3;
    f32x4 zf4 = {0.f, 0.f, 0.f, 0.f};
    MKSEL

    int pb = (blockIdx.x << 4) + (wid << 2) + g;       // this lane's build point
    int b = pb >> 15, n = pb & (NPTS - 1);
    int nb = nidx[((size_t)pb << 4) + c16];

    // issue neighbor-feature gather early
    const bf16x8* gsrc = (const bf16x8*)(f_pc + (((size_t)(b * NPTS + nb)) << 5));
    bf16x8 gv0 = gsrc[0], gv1 = gsrc[1], gv2 = gsrc[2], gv3 = gsrc[3];

    // rel-pos inputs
    const float* cx = xyz + (size_t)(b * NPTS + n) * 3;
    const float* nx = xyz + (size_t)(b * NPTS + nb) * 3;
    float c0 = cx[0], c1 = cx[1], c2 = cx[2];
    float x0 = nx[0], x1 = nx[1], x2 = nx[2];
    float r0 = c0 - x0, r1 = c1 - x1, r2 = c2 - x2;
    float dist = sqrtf(r0 * r0 + r1 * r1 + r2 * r2);

    // stage in10 bf16 (zero-padded to 32) into feat cols 32..63
    {
        uint4 u0; u0.x = pk2(dist, r0); u0.y = pk2(r1, r2); u0.z = pk2(c0, c1); u0.w = pk2(c2, x0);
        uint4 u1; u1.x = pk2(x1, x2); u1.y = 0; u1.z = 0; u1.w = 0;
        uint4 z4; z4.x = 0; z4.y = 0; z4.z = 0; z4.w = 0;
        *(uint4*)&feat[wid][lane][32] = u0;
        *(uint4*)&feat[wid][lane][40] = u1;
        *(uint4*)&feat[wid][lane][48] = z4;
        *(uint4*)&feat[wid][lane][56] = z4;
    }
    // FXYZ MFMA: read all B-frags before overwrite (w1p direct from global)
    {
        bf16x8 xb0 = *(const bf16x8*)&feat[wid][ 0 + c16][32 + g8];
        bf16x8 xb1 = *(const bf16x8*)&feat[wid][16 + c16][32 + g8];
        bf16x8 xb2 = *(const bf16x8*)&feat[wid][32 + c16][32 + g8];
        bf16x8 xb3 = *(const bf16x8*)&feat[wid][48 + c16][32 + g8];
        bf16x8 wa0 = *(const bf16x8*)&w1pg[(     c16) * 40 + g8];
        bf16x8 wa1 = *(const bf16x8*)&w1pg[(16 + c16) * 40 + g8];
        f32x4 bi0 = *(const f32x4*)&bb_b1[g4];
        f32x4 bi1 = *(const f32x4*)&bb_b1[16 + g4];
        f32x4 f00 = MF(wa0, xb0, bi0);
        f32x4 f01 = MF(wa0, xb1, bi0);
        f32x4 f02 = MF(wa0, xb2, bi0);
        f32x4 f03 = MF(wa0, xb3, bi0);
        f32x4 f10 = MF(wa1, xb0, bi1);
        f32x4 f11 = MF(wa1, xb1, bi1);
        f32x4 f12 = MF(wa1, xb2, bi1);
        f32x4 f13 = MF(wa1, xb3, bi1);
        WBX(0, 0, f00) WBX(0, 1, f01) WBX(0, 2, f02) WBX(0, 3, f03)
        WBX(1, 0, f10) WBX(1, 1, f11) WBX(1, 2, f12) WBX(1, 3, f13)
    }
    // gathered neighbor features (ch 0..31)
    *(bf16x8*)&feat[wid][lane][0]  = gv0;
    *(bf16x8*)&feat[wid][lane][8]  = gv1;
    *(bf16x8*)&feat[wid][lane][16] = gv2;
    *(bf16x8*)&feat[wid][lane][24] = gv3;

    LOAD_AFC(fcb1g)

    ATT_NI(0) ATT_NI(1) ATT_NI(2) ATT_NI(3)
    __syncthreads();

    // out-MLP via MFMA: waves 0,1 -> mi; prefolded aw from global (L2)
    if (wid < 2) {
        union { bf16x8 v; uint4 u; } bb0, bb1;
        QFRAG(bb0, 0)
        QFRAG(bb1, 32)
        int o = (wid << 4) + c16;
        bf16x8 aw0 = *(const bf16x8*)&awb1g[o * 64 + g8];
        bf16x8 aw1 = *(const bf16x8*)&awb1g[o * 64 + 32 + g8];
        f32x4 acc = *(const f32x4*)&att_b[(wid << 4) + g4];
        acc = MF(aw0, bb0.v, acc);
        acc = MF(aw1, bb1.v, acc);
        int p = (blockIdx.x << 4) + c16;
        int o0 = (wid << 4) + g4;
        uint2 st;
        st.x = pk2(fmaxf(acc[0], 0.f), fmaxf(acc[1], 0.f));
        st.y = pk2(fmaxf(acc[2], 0.f), fmaxf(acc[3], 0.f));
        *(uint2*)(f_agg + (((size_t)p) << 5) + o0) = st;
    }
}

// ---------------- Kernel 3: stage-2 -> fagg2 bf16 point-major (B*N, 64) ----------------
__global__ __launch_bounds__(256, 3) void k3_stage2(
    const float* __restrict__ xyz, const int* __restrict__ nidx,
    const ushort* __restrict__ f_agg,
    const float* __restrict__ bb_b1, const float* __restrict__ bb_b2,
    const ushort* __restrict__ fcb2g, const ushort* __restrict__ w1pg,
    const ushort* __restrict__ w2bg, const ushort* __restrict__ awb2g,
    const float* __restrict__ att_b,
    ushort* __restrict__ fagg2b)
{
    __shared__ __align__(16) ushort feat[4][64][72];
    __shared__ __align__(16) unsigned qe[16][68];

    int tid = threadIdx.x;
    int wid = tid >> 6, lane = tid & 63;
    int g = lane >> 4, c16 = lane & 15;
    int g4 = g << 2, g8 = g << 3;
    f32x4 zf4 = {0.f, 0.f, 0.f, 0.f};
    MKSEL

    int pb = (blockIdx.x << 4) + (wid << 2) + g;
    int b = pb >> 15, n = pb & (NPTS - 1);
    int nb = nidx[((size_t)pb << 4) + c16];

    const bf16x8* gsrc = (const bf16x8*)(f_agg + (((size_t)(b * NPTS + nb)) << 5));
    bf16x8 gv0 = gsrc[0], gv1 = gsrc[1], gv2 = gsrc[2], gv3 = gsrc[3];

    const float* cx = xyz + (size_t)(b * NPTS + n) * 3;
    const float* nx = xyz + (size_t)(b * NPTS + nb) * 3;
    float c0 = cx[0], c1 = cx[1], c2 = cx[2];
    float x0 = nx[0], x1 = nx[1], x2 = nx[2];
    float r0 = c0 - x0, r1 = c1 - x1, r2 = c2 - x2;
    float dist = sqrtf(r0 * r0 + r1 * r1 + r2 * r2);

    // stage in10
    {
        uint4 u0; u0.x = pk2(dist, r0); u0.y = pk2(r1, r2); u0.z = pk2(c0, c1); u0.w = pk2(c2, x0);
        uint4 u1; u1.x = pk2(x1, x2); u1.y = 0; u1.z = 0; u1.w = 0;
        uint4 z4; z4.x = 0; z4.y = 0; z4.z = 0; z4.w = 0;
        *(uint4*)&feat[wid][lane][32] = u0;
        *(uint4*)&feat[wid][lane][40] = u1;
        *(uint4*)&feat[wid][lane][48] = z4;
        *(uint4*)&feat[wid][lane][56] = z4;
    }
    // FXYZ MFMA -> stage-1 fx in cols 32..63 (w1p direct from global)
    {
        bf16x8 xb0 = *(const bf16x8*)&feat[wid][ 0 + c16][32 + g8];
        bf16x8 xb1 = *(const bf16x8*)&feat[wid][16 + c16][32 + g8];
        bf16x8 xb2 = *(const bf16x8*)&feat[wid][32 + c16][32 + g8];
        bf16x8 xb3 = *(const bf16x8*)&feat[wid][48 + c16][32 + g8];
        bf16x8 wa0 = *(const bf16x8*)&w1pg[(     c16) * 40 + g8];
        bf16x8 wa1 = *(const bf16x8*)&w1pg[(16 + c16) * 40 + g8];
        f32x4 bi0 = *(const f32x4*)&bb_b1[g4];
        f32x4 bi1 = *(const f32x4*)&bb_b1[16 + g4];
        f32x4 f00 = MF(wa0, xb0, bi0);
        f32x4 f01 = MF(wa0, xb1, bi0);
        f32x4 f02 = MF(wa0, xb2, bi0);
        f32x4 f03 = MF(wa0, xb3, bi0);
        f32x4 f10 = MF(wa1, xb0, bi1);
        f32x4 f11 = MF(wa1, xb1, bi1);
        f32x4 f12 = MF(wa1, xb2, bi1);
        f32x4 f13 = MF(wa1, xb3, bi1);
        WBX(0, 0, f00) WBX(0, 1, f01) WBX(0, 2, f02) WBX(0, 3, f03)
        WBX(1, 0, f10) WBX(1, 1, f11) WBX(1, 2, f12) WBX(1, 3, f13)
    }
    // bb_w2 A-fragments: prefolded bf16 from global (L2)
    bf16x8 aw20 = *(const bf16x8*)&w2bg[(     c16) * 32 + g8];
    bf16x8 aw21 = *(const bf16x8*)&w2bg[(16 + c16) * 32 + g8];
    // fx B-frags (read before overwrite), then f_xyz2 = relu(bn(bb_w2 @ fx))
    {
        bf16x8 bfx0 = *(const bf16x8*)&feat[wid][ 0 + c16][32 + g8];
        bf16x8 bfx1 = *(const bf16x8*)&feat[wid][16 + c16][32 + g8];
        bf16x8 bfx2 = *(const bf16x8*)&feat[wid][32 + c16][32 + g8];
        bf16x8 bfx3 = *(const bf16x8*)&feat[wid][48 + c16][32 + g8];
        f32x4 bi0 = *(const f32x4*)&bb_b2[     g4];
        f32x4 bi1 = *(const f32x4*)&bb_b2[16 + g4];
        f32x4 a00 = MF(aw20, bfx0, bi0);
        f32x4 a01 = MF(aw20, bfx1, bi0);
        f32x4 a02 = MF(aw20, bfx2, bi0);
        f32x4 a03 = MF(aw20, bfx3, bi0);
        f32x4 a10 = MF(aw21, bfx0, bi1);
        f32x4 a11 = MF(aw21, bfx1, bi1);
        f32x4 a12 = MF(aw21, bfx2, bi1);
        f32x4 a13 = MF(aw21, bfx3, bi1);
        WBX(0, 0, a00) WBX(0, 1, a01) WBX(0, 2, a02) WBX(0, 3, a03)
        WBX(1, 0, a10) WBX(1, 1, a11) WBX(1, 2, a12) WBX(1, 3, a13)
    }
    // gathered f_agg neighbor features (ch 0..31)
    *(bf16x8*)&feat[wid][lane][0]  = gv0;
    *(bf16x8*)&feat[wid][lane][8]  = gv1;
    *(bf16x8*)&feat[wid][lane][16] = gv2;
    *(bf16x8*)&feat[wid][lane][24] = gv3;

    LOAD_AFC(fcb2g)

    ATT_NI(0) ATT_NI(1) ATT_NI(2) ATT_NI(3)
    __syncthreads();

    // out-MLP via MFMA: wave wid -> mi; prefolded aw from global; bf16 store
    {
        union { bf16x8 v; uint4 u; } bb0, bb1;
        QFRAG(bb0, 0)
        QFRAG(bb1, 32)
        int o = (wid << 4) + c16;
        bf16x8 aw0 = *(const bf16x8*)&awb2g[o * 64 + g8];
        bf16x8 aw1 = *(const bf16x8*)&awb2g[o * 64 + 32 + g8];
        f32x4 acc = *(const f32x4*)&att_b[(wid << 4) + g4];
        acc = MF(aw0, bb0.v, acc);
        acc = MF(aw1, bb1.v, acc);
        int p = (blockIdx.x << 4) + c16;
        int o0 = (wid << 4) + g4;
        uint2 st;
        st.x = pk2(fmaxf(acc[0], 0.f), fmaxf(acc[1], 0.f));
        st.y = pk2(fmaxf(acc[2], 0.f), fmaxf(acc[3], 0.f));
        *(uint2*)(fagg2b + (((size_t)p) << 6) + o0) = st;
    }
}

// ---------------- Kernel 4: MFMA GEMM out[128 x pts] = Wcat[128x96] @ X[96 x pts] ----------------
__global__ __launch_bounds__(256, 4) void k4_final(
    const ushort* __restrict__ fagg2b, const ushort* __restrict__ featpm,
    const ushort* __restrict__ wcatg,
    const float* __restrict__ b_mlp2, const float* __restrict__ b_sc,
    float* __restrict__ out)
{
    int tid = threadIdx.x;
    int wid = tid >> 6, lane = tid & 63;
    int c16 = lane & 15, g = lane >> 4;
    int g4 = g << 2, g8 = g << 3;
    int p0 = blockIdx.x << 7;               // 128 points per block
    int o0 = wid << 5;

    bf16x8 A[2][3];
#pragma unroll
    for (int mi = 0; mi < 2; ++mi) {
        int o = o0 + mi * 16 + c16;
        A[mi][0] = *(const bf16x8*)&wcatg[o * 96 + g8];
        A[mi][1] = *(const bf16x8*)&wcatg[o * 96 + 32 + g8];
        A[mi][2] = *(const bf16x8*)&wcatg[o * 96 + 64 + g8];
    }
    float bias0[4], bias1[4];
#pragma unroll
    for (int r = 0; r < 4; ++r) {
        int oa = o0 + g4 + r;
        int ob = o0 + 16 + g4 + r;
        bias0[r] = b_mlp2[oa] + b_sc[oa];
        bias1[r] = b_mlp2[ob] + b_sc[ob];
    }

    int bb = p0 >> 15;                      // whole block same batch (p0 128-aligned)
#pragma unroll
    for (int ni = 0; ni < 8; ++ni) {
        int pt = p0 + ni * 16 + c16;
        bf16x8 B0 = *(const bf16x8*)&fagg2b[((size_t)pt << 6) + g8];
        bf16x8 B1 = *(const bf16x8*)&fagg2b[((size_t)pt << 6) + 32 + g8];
        bf16x8 B2 = *(const bf16x8*)&featpm[((size_t)pt << 5) + g8];
        f32x4 acc0 = {bias0[0], bias0[1], bias0[2], bias0[3]};
        f32x4 acc1 = {bias1[0], bias1[1], bias1[2], bias1[3]};
        acc0 = MF(A[0][0], B0, acc0);
        acc0 = MF(A[0][1], B1, acc0);
        acc0 = MF(A[0][2], B2, acc0);
        acc1 = MF(A[1][0], B0, acc1);
        acc1 = MF(A[1][1], B1, acc1);
        acc1 = MF(A[1][2], B2, acc1);
        int nn = pt & (NPTS - 1);
#pragma unroll
        for (int r = 0; r < 4; ++r) {
            float v0 = acc0[r];
            v0 = (v0 >= 0.f) ? v0 : 0.2f * v0;
            out[((bb * DOUT + o0 + g4 + r) << 15) + nn] = v0;
            float v1 = acc1[r];
            v1 = (v1 >= 0.f) ? v1 : 0.2f * v1;
            out[((bb * DOUT + o0 + 16 + g4 + r) << 15) + nn] = v1;
        }
    }
}

extern "C" void kernel_launch(void* const* d_in, const int* in_sizes, int n_in,
                              void* d_out, int out_size, void* d_ws, size_t ws_size,
                              hipStream_t stream) {
    const float* feature = (const float*)d_in[0];
    const float* xyz     = (const float*)d_in[1];
    const float* w_mlp1  = (const float*)d_in[2];
    const float* g_mlp1  = (const float*)d_in[3];
    const float* b_mlp1  = (const float*)d_in[4];
    const float* bb_w1   = (const float*)d_in[5];
    const float* bb_g1   = (const float*)d_in[6];
    const float* bb_b1   = (const float*)d_in[7];
    const float* att1_fc = (const float*)d_in[8];
    const float* att1_w  = (const float*)d_in[9];
    const float* att1_g  = (const float*)d_in[10];
    const float* att1_b  = (const float*)d_in[11];
    const float* bb_w2   = (const float*)d_in[12];
    const float* bb_g2   = (const float*)d_in[13];
    const float* bb_b2   = (const float*)d_in[14];
    const float* att2_fc = (const float*)d_in[15];
    const float* att2_w  = (const float*)d_in[16];
    const float* att2_g  = (const float*)d_in[17];
    const float* att2_b  = (const float*)d_in[18];
    const float* w_mlp2  = (const float*)d_in[19];
    const float* g_mlp2  = (const float*)d_in[20];
    const float* b_mlp2  = (const float*)d_in[21];
    const float* w_sc    = (const float*)d_in[22];
    const float* g_sc    = (const float*)d_in[23];
    const float* b_sc    = (const float*)d_in[24];
    const int*   nidx    = (const int*)d_in[25];
    float* out = (float*)d_out;

    ushort* f_pc_bf  = (ushort*)d_ws;                              // B*N*32 bf16
    ushort* f_agg_bf = f_pc_bf + (size_t)NB * NPTS * 32;           // B*N*32 bf16
    ushort* featpm   = f_agg_bf + (size_t)NB * NPTS * 32;          // B*N*32 bf16
    ushort* fagg2b   = featpm + (size_t)NB * NPTS * 32;            // B*N*64 bf16
    ushort* fcb1g    = fagg2b + (size_t)NB * NPTS * 64;            // 4096
    ushort* fcb2g    = fcb1g + 4096;                               // 4096
    ushort* awb1g    = fcb2g + 4096;                               // 2048
    ushort* awb2g    = awb1g + 2048;                               // 4096
    ushort* w2bg     = awb2g + 4096;                               // 1024
    ushort* w1pg     = w2bg + 1024;                                // 1280
    ushort* wcatg    = w1pg + 1280;                                // 12288

    k0_prep<<<48, 256, 0, stream>>>(att1_fc, att2_fc, att1_w, att1_g,
                                    att2_w, att2_g, bb_w1, bb_g1, bb_w2, bb_g2,
                                    w_mlp2, g_mlp2, w_sc, g_sc,
                                    fcb1g, fcb2g, awb1g, awb2g, w2bg, w1pg, wcatg);
    k1_mlp1<<<NB * NPTS / 256, 256, 0, stream>>>(feature, w_mlp1, g_mlp1, b_mlp1,
                                                 f_pc_bf, featpm);
    k2_stage1<<<NB * NPTS / 16, 256, 0, stream>>>(xyz, nidx, f_pc_bf,
                                                  bb_b1, fcb1g, w1pg, awb1g, att1_b,
                                                  f_agg_bf);
    k3_stage2<<<NB * NPTS / 16, 256, 0, stream>>>(xyz, nidx, f_agg_bf,
                                                  bb_b1, bb_b2, fcb2g, w1pg, w2bg, awb2g,
                                                  att2_b, fagg2b);
    k4_final<<<NB * NPTS / 128, 256, 0, stream>>>(fagg2b, featpm, wcatg,
                                                  b_mlp2, b_sc, out);
}

// Round 20
// 115.105 us; speedup vs baseline: 1.0257x; 1.0257x over previous
//
#include <hip/hip_runtime.h>
#include <math.h>

#define NPTS 32768
#define NB 2
#define CIN 32
#define H 32
#define D 64
#define DOUT 128
#define BN_RS 0.99999500003749981f   // 1/sqrt(1 + 1e-5)
#define LOG2E 1.44269504088896341f

typedef __attribute__((ext_vector_type(8))) short bf16x8;
typedef __attribute__((ext_vector_type(4))) short bf16x4;
typedef __attribute__((ext_vector_type(4))) float f32x4;

__device__ __forceinline__ ushort f2b(float f) {
    union { float f; unsigned u; } v; v.f = f;
    unsigned r = v.u + 0x7fffu + ((v.u >> 16) & 1u);   // RNE
    return (ushort)(r >> 16);
}
__device__ __forceinline__ float b2f(ushort u) {
    union { unsigned u; float f; } v; v.u = ((unsigned)u) << 16; return v.f;
}
// pack two f32 -> bf16x2 dword via gfx950 v_cvt_pk_bf16_f32 (1 inst); lo = f0, hi = f1
__device__ __forceinline__ unsigned pk2(float f0, float f1) {
    unsigned r;
    asm("v_cvt_pk_bf16_f32 %0, %1, %2" : "=v"(r) : "v"(f0), "v"(f1));
    return r;
}
// unpack (Q,E) dword -> Q/E
__device__ __forceinline__ float qdiv(unsigned u) {
    float q = __builtin_bit_cast(float, u << 16);
    float e = __builtin_bit_cast(float, u & 0xffff0000u);
    return __fdividef(q, e);
}
// raw 2^x (weights pre-scaled by log2e)
__device__ __forceinline__ float ex2(float x) {
    float r; asm("v_exp_f32 %0, %1" : "=v"(r) : "v"(x)); return r;
}
// cross-row sums via gfx950 permlane swaps (VALU pipe, no DS)
__device__ __forceinline__ float xsum16(float x) {
    float a = x, b = x;
    asm("v_permlane16_swap_b32 %0, %1" : "+v"(a), "+v"(b));
    return a + b;
}
__device__ __forceinline__ float xsum32(float x) {
    float a = x, b = x;
    asm("v_permlane32_swap_b32 %0, %1" : "+v"(a), "+v"(b));
    return a + b;
}
#define MF(a, b, c) __builtin_amdgcn_mfma_f32_16x16x32_bf16(a, b, c, 0, 0, 0)

// WBX: write relu'd C tile (mi,ni) to feat cols 32..63  (C: row=channel, col=position)
#define WBX(mi, ni, A) { uint2 _w;                                                \
    _w.x = pk2(fmaxf(A[0], 0.f), fmaxf(A[1], 0.f));                               \
    _w.y = pk2(fmaxf(A[2], 0.f), fmaxf(A[3], 0.f));                               \
    *(uint2*)&feat[wid][(ni) * 16 + c16][32 + (mi) * 16 + g4] = _w; }

// ---- transposed attention core: L^T = feat @ fc^T -> k on rows ----
#define ATT_CG(ni, cg, F0, F1, AF, SEL) {                                         \
    f32x4 ac = zf4;                                                               \
    ac = MF(a0_, F0, ac);                                                         \
    ac = MF(a1_, F1, ac);                                                         \
    f32x4 fv4 = MF(AF, SEL, zf4);                                                 \
    float e0 = ex2(ac[0]), e1 = ex2(ac[1]), e2 = ex2(ac[2]), e3 = ex2(ac[3]);     \
    float E = (e0 + e1) + (e2 + e3);                                              \
    float Q = e0 * fv4[0]; Q = fmaf(e1, fv4[1], Q);                               \
    Q = fmaf(e2, fv4[2], Q); Q = fmaf(e3, fv4[3], Q);                             \
    E = xsum32(xsum16(E));                                                        \
    Q = xsum32(xsum16(Q));                                                        \
    if (g == 0) qe[(wid << 2) + (ni)][(cg) * 16 + c16] = pk2(Q, E); }
#define ATT_NI(ni) {                                                              \
    bf16x8 a0_ = *(const bf16x8*)&feat[wid][(ni) * 16 + c16][g8];                 \
    bf16x8 a1_ = *(const bf16x8*)&feat[wid][(ni) * 16 + c16][32 + g8];            \
    ATT_CG(ni, 0, afc0_0, afc0_1, a0_, selLo.v) ATT_CG(ni, 1, afc1_0, afc1_1, a0_, selHi.v) \
    ATT_CG(ni, 2, afc2_0, afc2_1, a1_, selLo.v) ATT_CG(ni, 3, afc3_0, afc3_1, a1_, selHi.v) }

// build constant selector B-fragments: selLo[k][col]=d(k==col), selHi[k][col]=d(k==col+16)
#define MKSEL                                                                      \
    union { bf16x8 v; ushort s[8]; } selLo, selHi;                                 \
    _Pragma("unroll")                                                              \
    for (int j = 0; j < 8; ++j) {                                                  \
        selLo.s[j] = ((g8 + j) == c16)      ? (ushort)0x3F80 : (ushort)0;          \
        selHi.s[j] = ((g8 + j) == c16 + 16) ? (ushort)0x3F80 : (ushort)0;          \
    }

// build agg B-frags from qe (divide deferred to here)
#define QFRAG(bbv, base) {                                                        \
    uint4 _qa = *(const uint4*)&qe[c16][(base) + g8];                             \
    uint4 _qb = *(const uint4*)&qe[c16][(base) + g8 + 4];                         \
    bbv.u.x = pk2(qdiv(_qa.x), qdiv(_qa.y));                                      \
    bbv.u.y = pk2(qdiv(_qa.z), qdiv(_qa.w));                                      \
    bbv.u.z = pk2(qdiv(_qb.x), qdiv(_qb.y));                                      \
    bbv.u.w = pk2(qdiv(_qb.z), qdiv(_qb.w)); }

// LDS staging via raw uint4 copies from prefolded global arrays
#define STAGE_FCB(SRC)                                                             \
    {   int r = tid >> 2, cc = (tid & 3) << 4;                                     \
        *(uint4*)&fcb[r][cc]     = *(const uint4*)&(SRC)[r * 64 + cc];             \
        *(uint4*)&fcb[r][cc + 8] = *(const uint4*)&(SRC)[r * 64 + cc + 8];         \
        if (tid < 160) {                                                           \
            int rr = tid / 5, c2 = (tid % 5) << 3;                                 \
            *(uint4*)&w1p[rr][c2] = *(const uint4*)&w1pg[rr * 40 + c2];            \
        }                                                                          \
    }

// ---------------- Kernel 0: one-time weight prefold -> bf16 workspace ----------------
__global__ __launch_bounds__(256) void k0_prep(
    const float* __restrict__ att1_fc, const float* __restrict__ att2_fc,
    const float* __restrict__ att1_w, const float* __restrict__ att1_g,
    const float* __restrict__ att2_w, const float* __restrict__ att2_g,
    const float* __restrict__ bb_w1, const float* __restrict__ bb_g1,
    const float* __restrict__ bb_w2, const float* __restrict__ bb_g2,
    ushort* __restrict__ fcb1g, ushort* __restrict__ fcb2g,
    ushort* __restrict__ awb1g, ushort* __restrict__ awb2g,
    ushort* __restrict__ w2bg, ushort* __restrict__ w1pg)
{
    int t = blockIdx.x * 256 + threadIdx.x;
    if (t < 4096) {
        fcb1g[t] = f2b(att1_fc[t] * LOG2E);
        fcb2g[t] = f2b(att2_fc[t] * LOG2E);
        awb2g[t] = f2b(att2_w[t] * (att2_g[t >> 6] * BN_RS));
    }
    if (t < 2048) awb1g[t] = f2b(att1_w[t] * (att1_g[t >> 6] * BN_RS));
    if (t < 1024) w2bg[t]  = f2b(bb_w2[t] * (bb_g2[t >> 5] * BN_RS));
    if (t < 1280) {
        int o = t / 40, k = t % 40;
        w1pg[t] = (k < 10) ? f2b(bb_w1[o * 10 + k] * (bb_g1[o] * BN_RS)) : (ushort)0;
    }
}

// ---------------- Kernel 1: f_pc = relu(bn(w_mlp1 @ feature)) -> bf16 (B*N,32) ----------------
__global__ __launch_bounds__(256, 4) void k1_mlp1(
    const float* __restrict__ feature, const float* __restrict__ w_mlp1,
    const float* __restrict__ g_mlp1, const float* __restrict__ b_mlp1,
    ushort* __restrict__ f_pc, ushort* __restrict__ featpm)
{
    int tid = threadIdx.x;
    int pg = blockIdx.x * 256 + tid;
    int b = pg >> 15, n = pg & (NPTS - 1);

    float x[CIN];
#pragma unroll
    for (int c = 0; c < CIN; ++c)
        x[c] = feature[((b * CIN + c) << 15) + n];

    float outv[CIN];
#pragma unroll
    for (int o = 0; o < CIN; ++o) {
        float s0 = 0.f, s1 = 0.f, s2 = 0.f, s3 = 0.f;
        const float* w = w_mlp1 + o * CIN;
#pragma unroll
        for (int c = 0; c < CIN; c += 4) {
            s0 = fmaf(w[c + 0], x[c + 0], s0);
            s1 = fmaf(w[c + 1], x[c + 1], s1);
            s2 = fmaf(w[c + 2], x[c + 2], s2);
            s3 = fmaf(w[c + 3], x[c + 3], s3);
        }
        float acc = (s0 + s1) + (s2 + s3);
        outv[o] = fmaxf(fmaf(acc, g_mlp1[o] * BN_RS, b_mlp1[o]), 0.f);
    }
    uint4* dst = (uint4*)(f_pc + ((size_t)pg << 5));
    uint4* dst2 = (uint4*)(featpm + ((size_t)pg << 5));
#pragma unroll
    for (int j = 0; j < 4; ++j) {
        uint4 u;
        u.x = pk2(outv[8 * j + 0], outv[8 * j + 1]);
        u.y = pk2(outv[8 * j + 2], outv[8 * j + 3]);
        u.z = pk2(outv[8 * j + 4], outv[8 * j + 5]);
        u.w = pk2(outv[8 * j + 6], outv[8 * j + 7]);
        dst[j] = u;
        uint4 v;
        v.x = pk2(x[8 * j + 0], x[8 * j + 1]);
        v.y = pk2(x[8 * j + 2], x[8 * j + 3]);
        v.z = pk2(x[8 * j + 4], x[8 * j + 5]);
        v.w = pk2(x[8 * j + 6], x[8 * j + 7]);
        dst2[j] = v;
    }
}

// ---------------- Kernel 2: stage-1 -> f_agg bf16 (B*N, 32) ----------------
__global__ __launch_bounds__(256, 3) void k2_stage1(
    const float* __restrict__ xyz, const int* __restrict__ nidx,
    const ushort* __restrict__ f_pc,
    const float* __restrict__ bb_b1,
    const ushort* __restrict__ fcb1g, const ushort* __restrict__ w1pg,
    const ushort* __restrict__ awb1g, const float* __restrict__ att_b,
    ushort* __restrict__ f_agg)
{
    __shared__ __align__(16) ushort feat[4][64][72];   // per-wave 64 pos x 64 ch bf16
    __shared__ __align__(16) unsigned qe[16][68];      // packed (Q,E) per point x channel
    __shared__ __align__(16) ushort fcb[64][72];       // att1_fc * log2e, bf16
    __shared__ __align__(16) ushort w1p[32][40];       // folded bb_w1, K-padded to 32

    int tid = threadIdx.x;
    STAGE_FCB(fcb1g)
    __syncthreads();

    int wid = tid >> 6, lane = tid & 63;
    int g = lane >> 4, c16 = lane & 15;
    int g4 = g << 2, g8 = g << 3;
    f32x4 zf4 = {0.f, 0.f, 0.f, 0.f};
    MKSEL

    int pb = (blockIdx.x << 4) + (wid << 2) + g;       // this lane's build point
    int b = pb >> 15, n = pb & (NPTS - 1);
    int nb = nidx[((size_t)pb << 4) + c16];

    // issue neighbor-feature gather early
    const bf16x8* gsrc = (const bf16x8*)(f_pc + (((size_t)(b * NPTS + nb)) << 5));
    bf16x8 gv0 = gsrc[0], gv1 = gsrc[1], gv2 = gsrc[2], gv3 = gsrc[3];

    // rel-pos inputs
    const float* cx = xyz + (size_t)(b * NPTS + n) * 3;
    const float* nx = xyz + (size_t)(b * NPTS + nb) * 3;
    float c0 = cx[0], c1 = cx[1], c2 = cx[2];
    float x0 = nx[0], x1 = nx[1], x2 = nx[2];
    float r0 = c0 - x0, r1 = c1 - x1, r2 = c2 - x2;
    float dist = sqrtf(r0 * r0 + r1 * r1 + r2 * r2);

    // stage in10 bf16 (zero-padded to 32) into feat cols 32..63
    {
        uint4 u0; u0.x = pk2(dist, r0); u0.y = pk2(r1, r2); u0.z = pk2(c0, c1); u0.w = pk2(c2, x0);
        uint4 u1; u1.x = pk2(x1, x2); u1.y = 0; u1.z = 0; u1.w = 0;
        uint4 z4; z4.x = 0; z4.y = 0; z4.z = 0; z4.w = 0;
        *(uint4*)&feat[wid][lane][32] = u0;
        *(uint4*)&feat[wid][lane][40] = u1;
        *(uint4*)&feat[wid][lane][48] = z4;
        *(uint4*)&feat[wid][lane][56] = z4;
    }
    // FXYZ MFMA: read all B-frags before overwrite
    {
        bf16x8 xb0 = *(const bf16x8*)&feat[wid][ 0 + c16][32 + g8];
        bf16x8 xb1 = *(const bf16x8*)&feat[wid][16 + c16][32 + g8];
        bf16x8 xb2 = *(const bf16x8*)&feat[wid][32 + c16][32 + g8];
        bf16x8 xb3 = *(const bf16x8*)&feat[wid][48 + c16][32 + g8];
        bf16x8 wa0 = *(const bf16x8*)&w1p[     c16][g8];
        bf16x8 wa1 = *(const bf16x8*)&w1p[16 + c16][g8];
        f32x4 bi0 = *(const f32x4*)&bb_b1[g4];
        f32x4 bi1 = *(const f32x4*)&bb_b1[16 + g4];
        f32x4 f00 = MF(wa0, xb0, bi0);
        f32x4 f01 = MF(wa0, xb1, bi0);
        f32x4 f02 = MF(wa0, xb2, bi0);
        f32x4 f03 = MF(wa0, xb3, bi0);
        f32x4 f10 = MF(wa1, xb0, bi1);
        f32x4 f11 = MF(wa1, xb1, bi1);
        f32x4 f12 = MF(wa1, xb2, bi1);
        f32x4 f13 = MF(wa1, xb3, bi1);
        WBX(0, 0, f00) WBX(0, 1, f01) WBX(0, 2, f02) WBX(0, 3, f03)
        WBX(1, 0, f10) WBX(1, 1, f11) WBX(1, 2, f12) WBX(1, 3, f13)
    }
    // gathered neighbor features (ch 0..31)
    *(bf16x8*)&feat[wid][lane][0]  = gv0;
    *(bf16x8*)&feat[wid][lane][8]  = gv1;
    *(bf16x8*)&feat[wid][lane][16] = gv2;
    *(bf16x8*)&feat[wid][lane][24] = gv3;

    // fc B-fragments from LDS (transposed MFMA: B cols = output channels)
    bf16x8 afc0_0 = *(const bf16x8*)&fcb[ 0 + c16][     g8];
    bf16x8 afc0_1 = *(const bf16x8*)&fcb[ 0 + c16][32 + g8];
    bf16x8 afc1_0 = *(const bf16x8*)&fcb[16 + c16][     g8];
    bf16x8 afc1_1 = *(const bf16x8*)&fcb[16 + c16][32 + g8];
    bf16x8 afc2_0 = *(const bf16x8*)&fcb[32 + c16][     g8];
    bf16x8 afc2_1 = *(const bf16x8*)&fcb[32 + c16][32 + g8];
    bf16x8 afc3_0 = *(const bf16x8*)&fcb[48 + c16][     g8];
    bf16x8 afc3_1 = *(const bf16x8*)&fcb[48 + c16][32 + g8];

    ATT_NI(0) ATT_NI(1) ATT_NI(2) ATT_NI(3)
    __syncthreads();

    // out-MLP via MFMA: waves 0,1 -> mi; prefolded aw from global (L2)
    if (wid < 2) {
        union { bf16x8 v; uint4 u; } bb0, bb1;
        QFRAG(bb0, 0)
        QFRAG(bb1, 32)
        int o = (wid << 4) + c16;
        bf16x8 aw0 = *(const bf16x8*)&awb1g[o * 64 + g8];
        bf16x8 aw1 = *(const bf16x8*)&awb1g[o * 64 + 32 + g8];
        f32x4 acc = *(const f32x4*)&att_b[(wid << 4) + g4];
        acc = MF(aw0, bb0.v, acc);
        acc = MF(aw1, bb1.v, acc);
        int p = (blockIdx.x << 4) + c16;
        int o0 = (wid << 4) + g4;
        uint2 st;
        st.x = pk2(fmaxf(acc[0], 0.f), fmaxf(acc[1], 0.f));
        st.y = pk2(fmaxf(acc[2], 0.f), fmaxf(acc[3], 0.f));
        *(uint2*)(f_agg + (((size_t)p) << 5) + o0) = st;
    }
}

// ---------------- Kernel 3: stage-2 -> fagg2 bf16 point-major (B*N, 64) ----------------
__global__ __launch_bounds__(256, 3) void k3_stage2(
    const float* __restrict__ xyz, const int* __restrict__ nidx,
    const ushort* __restrict__ f_agg,
    const float* __restrict__ bb_b1, const float* __restrict__ bb_b2,
    const ushort* __restrict__ fcb2g, const ushort* __restrict__ w1pg,
    const ushort* __restrict__ w2bg, const ushort* __restrict__ awb2g,
    const float* __restrict__ att_b,
    ushort* __restrict__ fagg2b)
{
    __shared__ __align__(16) ushort feat[4][64][72];
    __shared__ __align__(16) unsigned qe[16][68];
    __shared__ __align__(16) ushort fcb[64][72];
    __shared__ __align__(16) ushort w1p[32][40];

    int tid = threadIdx.x;
    STAGE_FCB(fcb2g)
    __syncthreads();

    int wid = tid >> 6, lane = tid & 63;
    int g = lane >> 4, c16 = lane & 15;
    int g4 = g << 2, g8 = g << 3;
    f32x4 zf4 = {0.f, 0.f, 0.f, 0.f};
    MKSEL

    int pb = (blockIdx.x << 4) + (wid << 2) + g;
    int b = pb >> 15, n = pb & (NPTS - 1);
    int nb = nidx[((size_t)pb << 4) + c16];

    const bf16x8* gsrc = (const bf16x8*)(f_agg + (((size_t)(b * NPTS + nb)) << 5));
    bf16x8 gv0 = gsrc[0], gv1 = gsrc[1], gv2 = gsrc[2], gv3 = gsrc[3];

    const float* cx = xyz + (size_t)(b * NPTS + n) * 3;
    const float* nx = xyz + (size_t)(b * NPTS + nb) * 3;
    float c0 = cx[0], c1 = cx[1], c2 = cx[2];
    float x0 = nx[0], x1 = nx[1], x2 = nx[2];
    float r0 = c0 - x0, r1 = c1 - x1, r2 = c2 - x2;
    float dist = sqrtf(r0 * r0 + r1 * r1 + r2 * r2);

    // stage in10
    {
        uint4 u0; u0.x = pk2(dist, r0); u0.y = pk2(r1, r2); u0.z = pk2(c0, c1); u0.w = pk2(c2, x0);
        uint4 u1; u1.x = pk2(x1, x2); u1.y = 0; u1.z = 0; u1.w = 0;
        uint4 z4; z4.x = 0; z4.y = 0; z4.z = 0; z4.w = 0;
        *(uint4*)&feat[wid][lane][32] = u0;
        *(uint4*)&feat[wid][lane][40] = u1;
        *(uint4*)&feat[wid][lane][48] = z4;
        *(uint4*)&feat[wid][lane][56] = z4;
    }
    // FXYZ MFMA -> stage-1 fx in cols 32..63
    {
        bf16x8 xb0 = *(const bf16x8*)&feat[wid][ 0 + c16][32 + g8];
        bf16x8 xb1 = *(const bf16x8*)&feat[wid][16 + c16][32 + g8];
        bf16x8 xb2 = *(const bf16x8*)&feat[wid][32 + c16][32 + g8];
        bf16x8 xb3 = *(const bf16x8*)&feat[wid][48 + c16][32 + g8];
        bf16x8 wa0 = *(const bf16x8*)&w1p[     c16][g8];
        bf16x8 wa1 = *(const bf16x8*)&w1p[16 + c16][g8];
        f32x4 bi0 = *(const f32x4*)&bb_b1[g4];
        f32x4 bi1 = *(const f32x4*)&bb_b1[16 + g4];
        f32x4 f00 = MF(wa0, xb0, bi0);
        f32x4 f01 = MF(wa0, xb1, bi0);
        f32x4 f02 = MF(wa0, xb2, bi0);
        f32x4 f03 = MF(wa0, xb3, bi0);
        f32x4 f10 = MF(wa1, xb0, bi1);
        f32x4 f11 = MF(wa1, xb1, bi1);
        f32x4 f12 = MF(wa1, xb2, bi1);
        f32x4 f13 = MF(wa1, xb3, bi1);
        WBX(0, 0, f00) WBX(0, 1, f01) WBX(0, 2, f02) WBX(0, 3, f03)
        WBX(1, 0, f10) WBX(1, 1, f11) WBX(1, 2, f12) WBX(1, 3, f13)
    }
    // bb_w2 A-fragments: prefolded bf16 from global (L2)
    bf16x8 aw20 = *(const bf16x8*)&w2bg[(     c16) * 32 + g8];
    bf16x8 aw21 = *(const bf16x8*)&w2bg[(16 + c16) * 32 + g8];
    // fx B-frags (read before overwrite), then f_xyz2 = relu(bn(bb_w2 @ fx))
    {
        bf16x8 bfx0 = *(const bf16x8*)&feat[wid][ 0 + c16][32 + g8];
        bf16x8 bfx1 = *(const bf16x8*)&feat[wid][16 + c16][32 + g8];
        bf16x8 bfx2 = *(const bf16x8*)&feat[wid][32 + c16][32 + g8];
        bf16x8 bfx3 = *(const bf16x8*)&feat[wid][48 + c16][32 + g8];
        f32x4 bi0 = *(const f32x4*)&bb_b2[     g4];
        f32x4 bi1 = *(const f32x4*)&bb_b2[16 + g4];
        f32x4 a00 = MF(aw20, bfx0, bi0);
        f32x4 a01 = MF(aw20, bfx1, bi0);
        f32x4 a02 = MF(aw20, bfx2, bi0);
        f32x4 a03 = MF(aw20, bfx3, bi0);
        f32x4 a10 = MF(aw21, bfx0, bi1);
        f32x4 a11 = MF(aw21, bfx1, bi1);
        f32x4 a12 = MF(aw21, bfx2, bi1);
        f32x4 a13 = MF(aw21, bfx3, bi1);
        WBX(0, 0, a00) WBX(0, 1, a01) WBX(0, 2, a02) WBX(0, 3, a03)
        WBX(1, 0, a10) WBX(1, 1, a11) WBX(1, 2, a12) WBX(1, 3, a13)
    }
    // gathered f_agg neighbor features (ch 0..31)
    *(bf16x8*)&feat[wid][lane][0]  = gv0;
    *(bf16x8*)&feat[wid][lane][8]  = gv1;
    *(bf16x8*)&feat[wid][lane][16] = gv2;
    *(bf16x8*)&feat[wid][lane][24] = gv3;

    bf16x8 afc0_0 = *(const bf16x8*)&fcb[ 0 + c16][     g8];
    bf16x8 afc0_1 = *(const bf16x8*)&fcb[ 0 + c16][32 + g8];
    bf16x8 afc1_0 = *(const bf16x8*)&fcb[16 + c16][     g8];
    bf16x8 afc1_1 = *(const bf16x8*)&fcb[16 + c16][32 + g8];
    bf16x8 afc2_0 = *(const bf16x8*)&fcb[32 + c16][     g8];
    bf16x8 afc2_1 = *(const bf16x8*)&fcb[32 + c16][32 + g8];
    bf16x8 afc3_0 = *(const bf16x8*)&fcb[48 + c16][     g8];
    bf16x8 afc3_1 = *(const bf16x8*)&fcb[48 + c16][32 + g8];

    ATT_NI(0) ATT_NI(1) ATT_NI(2) ATT_NI(3)
    __syncthreads();

    // out-MLP via MFMA: wave wid -> mi; prefolded aw from global; bf16 store
    {
        union { bf16x8 v; uint4 u; } bb0, bb1;
        QFRAG(bb0, 0)
        QFRAG(bb1, 32)
        int o = (wid << 4) + c16;
        bf16x8 aw0 = *(const bf16x8*)&awb2g[o * 64 + g8];
        bf16x8 aw1 = *(const bf16x8*)&awb2g[o * 64 + 32 + g8];
        f32x4 acc = *(const f32x4*)&att_b[(wid << 4) + g4];
        acc = MF(aw0, bb0.v, acc);
        acc = MF(aw1, bb1.v, acc);
        int p = (blockIdx.x << 4) + c16;
        int o0 = (wid << 4) + g4;
        uint2 st;
        st.x = pk2(fmaxf(acc[0], 0.f), fmaxf(acc[1], 0.f));
        st.y = pk2(fmaxf(acc[2], 0.f), fmaxf(acc[3], 0.f));
        *(uint2*)(fagg2b + (((size_t)p) << 6) + o0) = st;
    }
}

// ---------------- Kernel 4: MFMA GEMM out[128 x pts] = Wcat[128x96] @ X[96 x pts] ----------------
__global__ __launch_bounds__(256, 4) void k4_final(
    const ushort* __restrict__ fagg2b, const ushort* __restrict__ featpm,
    const float* __restrict__ w_mlp2, const float* __restrict__ g_mlp2, const float* __restrict__ b_mlp2,
    const float* __restrict__ w_sc, const float* __restrict__ g_sc, const float* __restrict__ b_sc,
    float* __restrict__ out)
{
    int tid = threadIdx.x;
    int wid = tid >> 6, lane = tid & 63;
    int c16 = lane & 15, g = lane >> 4;
    int g4 = g << 2, g8 = g << 3;
    int p0 = blockIdx.x << 7;               // 128 points per block
    int o0 = wid << 5;

    union { bf16x8 v; uint4 u; } A[2][3];
#pragma unroll
    for (int mi = 0; mi < 2; ++mi) {
        int o = o0 + mi * 16 + c16;
        float sm = g_mlp2[o] * BN_RS, ss = g_sc[o] * BN_RS;
        const float* wm = w_mlp2 + o * D;
        const float* ws = w_sc + o * CIN;
#pragma unroll
        for (int ks = 0; ks < 2; ++ks) {
            float4 wa = *(const float4*)&wm[ks * 32 + g8];
            float4 wb = *(const float4*)&wm[ks * 32 + g8 + 4];
            A[mi][ks].u.x = pk2(wa.x * sm, wa.y * sm);
            A[mi][ks].u.y = pk2(wa.z * sm, wa.w * sm);
            A[mi][ks].u.z = pk2(wb.x * sm, wb.y * sm);
            A[mi][ks].u.w = pk2(wb.z * sm, wb.w * sm);
        }
        float4 wa = *(const float4*)&ws[g8];
        float4 wb = *(const float4*)&ws[g8 + 4];
        A[mi][2].u.x = pk2(wa.x * ss, wa.y * ss);
        A[mi][2].u.y = pk2(wa.z * ss, wa.w * ss);
        A[mi][2].u.z = pk2(wb.x * ss, wb.y * ss);
        A[mi][2].u.w = pk2(wb.z * ss, wb.w * ss);
    }
    float bias0[4], bias1[4];
#pragma unroll
    for (int r = 0; r < 4; ++r) {
        int oa = o0 + g4 + r;
        int ob = o0 + 16 + g4 + r;
        bias0[r] = b_mlp2[oa] + b_sc[oa];
        bias1[r] = b_mlp2[ob] + b_sc[ob];
    }

    int bb = p0 >> 15;                      // whole block same batch (p0 128-aligned)
#pragma unroll
    for (int ni = 0; ni < 8; ++ni) {
        int pt = p0 + ni * 16 + c16;
        bf16x8 B0 = *(const bf16x8*)&fagg2b[((size_t)pt << 6) + g8];
        bf16x8 B1 = *(const bf16x8*)&fagg2b[((size_t)pt << 6) + 32 + g8];
        bf16x8 B2 = *(const bf16x8*)&featpm[((size_t)pt << 5) + g8];
        f32x4 acc0 = {bias0[0], bias0[1], bias0[2], bias0[3]};
        f32x4 acc1 = {bias1[0], bias1[1], bias1[2], bias1[3]};
        acc0 = MF(A[0][0].v, B0, acc0);
        acc0 = MF(A[0][1].v, B1, acc0);
        acc0 = MF(A[0][2].v, B2, acc0);
        acc1 = MF(A[1][0].v, B0, acc1);
        acc1 = MF(A[1][1].v, B1, acc1);
        acc1 = MF(A[1][2].v, B2, acc1);
        int nn = pt & (NPTS - 1);
#pragma unroll
        for (int r = 0; r < 4; ++r) {
            float v0 = acc0[r];
            v0 = (v0 >= 0.f) ? v0 : 0.2f * v0;
            out[((bb * DOUT + o0 + g4 + r) << 15) + nn] = v0;
            float v1 = acc1[r];
            v1 = (v1 >= 0.f) ? v1 : 0.2f * v1;
            out[((bb * DOUT + o0 + 16 + g4 + r) << 15) + nn] = v1;
        }
    }
}

extern "C" void kernel_launch(void* const* d_in, const int* in_sizes, int n_in,
                              void* d_out, int out_size, void* d_ws, size_t ws_size,
                              hipStream_t stream) {
    const float* feature = (const float*)d_in[0];
    const float* xyz     = (const float*)d_in[1];
    const float* w_mlp1  = (const float*)d_in[2];
    const float* g_mlp1  = (const float*)d_in[3];
    const float* b_mlp1  = (const float*)d_in[4];
    const float* bb_w1   = (const float*)d_in[5];
    const float* bb_g1   = (const float*)d_in[6];
    const float* bb_b1   = (const float*)d_in[7];
    const float* att1_fc = (const float*)d_in[8];
    const float* att1_w  = (const float*)d_in[9];
    const float* att1_g  = (const float*)d_in[10];
    const float* att1_b  = (const float*)d_in[11];
    const float* bb_w2   = (const float*)d_in[12];
    const float* bb_g2   = (const float*)d_in[13];
    const float* bb_b2   = (const float*)d_in[14];
    const float* att2_fc = (const float*)d_in[15];
    const float* att2_w  = (const float*)d_in[16];
    const float* att2_g  = (const float*)d_in[17];
    const float* att2_b  = (const float*)d_in[18];
    const float* w_mlp2  = (const float*)d_in[19];
    const float* g_mlp2  = (const float*)d_in[20];
    const float* b_mlp2  = (const float*)d_in[21];
    const float* w_sc    = (const float*)d_in[22];
    const float* g_sc    = (const float*)d_in[23];
    const float* b_sc    = (const float*)d_in[24];
    const int*   nidx    = (const int*)d_in[25];
    float* out = (float*)d_out;

    ushort* f_pc_bf  = (ushort*)d_ws;                              // B*N*32 bf16
    ushort* f_agg_bf = f_pc_bf + (size_t)NB * NPTS * 32;           // B*N*32 bf16
    ushort* featpm   = f_agg_bf + (size_t)NB * NPTS * 32;          // B*N*32 bf16
    ushort* fagg2b   = featpm + (size_t)NB * NPTS * 32;            // B*N*64 bf16
    ushort* fcb1g    = fagg2b + (size_t)NB * NPTS * 64;            // 4096
    ushort* fcb2g    = fcb1g + 4096;                               // 4096
    ushort* awb1g    = fcb2g + 4096;                               // 2048
    ushort* awb2g    = awb1g + 2048;                               // 4096
    ushort* w2bg     = awb2g + 4096;                               // 1024
    ushort* w1pg     = w2bg + 1024;                                // 1280

    k0_prep<<<16, 256, 0, stream>>>(att1_fc, att2_fc, att1_w, att1_g,
                                    att2_w, att2_g, bb_w1, bb_g1, bb_w2, bb_g2,
                                    fcb1g, fcb2g, awb1g, awb2g, w2bg, w1pg);
    k1_mlp1<<<NB * NPTS / 256, 256, 0, stream>>>(feature, w_mlp1, g_mlp1, b_mlp1,
                                                 f_pc_bf, featpm);
    k2_stage1<<<NB * NPTS / 16, 256, 0, stream>>>(xyz, nidx, f_pc_bf,
                                                  bb_b1, fcb1g, w1pg, awb1g, att1_b,
                                                  f_agg_bf);
    k3_stage2<<<NB * NPTS / 16, 256, 0, stream>>>(xyz, nidx, f_agg_bf,
                                                  bb_b1, bb_b2, fcb2g, w1pg, w2bg, awb2g,
                                                  att2_b, fagg2b);
    k4_final<<<NB * NPTS / 128, 256, 0, stream>>>(fagg2b, featpm,
                                                  w_mlp2, g_mlp2, b_mlp2,
                                                  w_sc, g_sc, b_sc, out);
}